// Round 7
// baseline (142.210 us; speedup 1.0000x reference)
//
#include <hip/hip_runtime.h>

#define HH 128
#define WW 128
#define BB 4
#define CC 64
#define CHN 21
#define NPIX (HH*WW)     // 16384
#define NTAP 24
#define PAD 4
#define PW 136
#define PH 136
#define PPLANE (PW*PH)   // 18496
#define PWQ (PW/4)       // 34
#define CG 7             // channels per prop thread
#define NCG (CHN/CG)     // 3
#define AGR 4            // affinity channel groups per block
#define ACH (CC/AGR)     // 16 channels per thread

// Compile-time tap offsets in the padded plane (row stride PW).
// Order: dil 1 (8 taps), dil 2 (8), dil 4 (8) — same order in both kernels.
constexpr int TAPOFF[NTAP] = {
    -PW-1, -PW, -PW+1, -1, 1, PW-1, PW, PW+1,
    -2*PW-2, -2*PW, -2*PW+2, -2, 2, 2*PW-2, 2*PW, 2*PW+2,
    -4*PW-4, -4*PW, -4*PW+4, -4, 4, 4*PW-4, 4*PW, 4*PW+4
};

__device__ __forceinline__ int clampi(int v, int lo, int hi) {
    return v < lo ? lo : (v > hi ? hi : v);
}

// ---- pad: edge-replicate feats AND mask into padded planes in one launch ---
__global__ __launch_bounds__(256) void pad_kernel(
    const float* __restrict__ feats, const float* __restrict__ mask,
    float* __restrict__ pfeats, float* __restrict__ pmask) {
    int t = blockIdx.x * blockDim.x + threadIdx.x;
    const int nfp = BB * CC;
    const int total = (nfp + BB * CHN) * PH * PWQ;
    if (t >= total) return;
    int q = t % PWQ;
    int rest = t / PWQ;
    int ph = rest % PH;
    int pl = rest / PH;
    const float* src;
    float* dst;
    if (pl < nfp) { src = feats + (size_t)pl * NPIX; dst = pfeats + (size_t)pl * PPLANE; }
    else { src = mask + (size_t)(pl - nfp) * NPIX; dst = pmask + (size_t)(pl - nfp) * PPLANE; }
    const float* sp = src + (size_t)clampi(ph - PAD, 0, HH - 1) * WW;
    float4 v;
    v.x = sp[clampi(q * 4 + 0 - PAD, 0, WW - 1)];
    v.y = sp[clampi(q * 4 + 1 - PAD, 0, WW - 1)];
    v.z = sp[clampi(q * 4 + 2 - PAD, 0, WW - 1)];
    v.w = sp[clampi(q * 4 + 3 - PAD, 0, WW - 1)];
    *((float4*)(dst + (size_t)ph * PW + q * 4)) = v;
}

// ---- fused affinity: block = 64 px x 4 channel-groups; LDS reduce ----------
// aff output layout: [b][6][NPIX][4] (tap-quad SoA, coalesced for prop).
__global__ __launch_bounds__(256) void affinity_kernel(
    const float* __restrict__ pfeats, float* __restrict__ aff) {
    __shared__ float red[AGR][64][NTAP + 1];   // stride 25: conflict-free

    int t = threadIdx.x;
    int g = t >> 6;                  // 0..3 channel group
    int px = t & 63;                 // 0..63 pixel in half-row
    int blk = blockIdx.x;            // 0..1023
    int w = (blk & 1) * 64 + px;
    int h = (blk >> 1) & 127;
    int b = blk >> 8;

    const float* base0 = pfeats + (size_t)(b * CC + g * ACH) * PPLANE
                       + (size_t)(h + PAD) * PW + (w + PAD);

    float acc[NTAP];
    #pragma unroll
    for (int k = 0; k < NTAP; ++k) acc[k] = 0.f;

    for (int c = 0; c < ACH; ++c) {
        const float* base = base0 + (size_t)c * PPLANE;
        float q = base[0];
        float sum = 3.f * q, ss = 3.f * q * q;   // center window x3 dilations
        float v[NTAP];
        #pragma unroll
        for (int k = 0; k < NTAP; ++k) {
            float x = base[TAPOFF[k]];
            v[k] = x;
            sum += x;
            ss = fmaf(x, x, ss);
        }
        float var = (ss - sum * sum * (1.f/27.f)) * (1.f/26.f);
        float inv = 1.f / (1e-8f + 0.1f * sqrtf(fmaxf(var, 0.f)));
        #pragma unroll
        for (int k = 0; k < NTAP; ++k)
            acc[k] = fmaf(fabsf(v[k] - q), inv, acc[k]);   // positive sum; negate later
    }

    #pragma unroll
    for (int k = 0; k < NTAP; ++k) red[g][px][k] = acc[k];
    __syncthreads();

    if (t < 64) {
        float s[NTAP];
        #pragma unroll
        for (int k = 0; k < NTAP; ++k)
            s[k] = (red[0][t][k] + red[1][t][k]) + (red[2][t][k] + red[3][t][k]);
        // score_k = -s_k/64; softmax with max-sub == exp((min_s - s_k)/64)
        float mn = s[0];
        #pragma unroll
        for (int k = 1; k < NTAP; ++k) mn = fminf(mn, s[k]);
        float e[NTAP];
        float tot = 0.f;
        #pragma unroll
        for (int k = 0; k < NTAP; ++k) {
            e[k] = __expf((mn - s[k]) * (1.f/CC));
            tot += e[k];
        }
        float ivt = 1.f / tot;
        int pix = h * WW + (blk & 1) * 64 + t;
        #pragma unroll
        for (int j = 0; j < 6; ++j) {
            float4 o = make_float4(e[4*j]*ivt, e[4*j+1]*ivt, e[4*j+2]*ivt, e[4*j+3]*ivt);
            *((float4*)(aff + (((size_t)b * 6 + j) * NPIX + pix) * 4)) = o;
        }
    }
}

// ---- prop: 1 px x 7 ch per thread; coalesced SoA aff; imm tap offsets ------
__global__ __launch_bounds__(256) void prop_kernel(
    const float* __restrict__ psrc_all, const float* __restrict__ aff,
    float* __restrict__ dst, int final_iter) {
    int idx = blockIdx.x * 256 + threadIdx.x;   // global px 0..65535
    int cg = blockIdx.y;                        // 0..2
    int w = idx & 127;
    int h = (idx >> 7) & 127;
    int b = idx >> 14;
    int pix = idx & (NPIX - 1);

    float A[NTAP];
    #pragma unroll
    for (int j = 0; j < 6; ++j) {
        float4 v = *((const float4*)(aff + (((size_t)b * 6 + j) * NPIX + pix) * 4));
        A[4*j] = v.x; A[4*j+1] = v.y; A[4*j+2] = v.z; A[4*j+3] = v.w;
    }

    #pragma unroll
    for (int cc = 0; cc < CG; ++cc) {
        int ch = cg * CG + cc;
        const float* base = psrc_all + (size_t)(b * CHN + ch) * PPLANE
                          + (size_t)(h + PAD) * PW + (w + PAD);
        float r = 0.f;
        #pragma unroll
        for (int k = 0; k < NTAP; ++k) r = fmaf(A[k], base[TAPOFF[k]], r);

        if (final_iter) {
            dst[(size_t)(b * CHN + ch) * NPIX + h * WW + w] = r;
        } else {
            float* pd = dst + (size_t)(b * CHN + ch) * PPLANE;
            int pr = (h + PAD) * PW;
            pd[pr + PAD + w] = r;
            float4 e = make_float4(r, r, r, r);
            if (w == 0)      *((float4*)(pd + pr)) = e;
            if (w == WW-1)   *((float4*)(pd + pr + PAD + WW)) = e;
            if (h == 0) {
                #pragma unroll
                for (int rr = 0; rr < PAD; ++rr) {
                    pd[rr * PW + PAD + w] = r;
                    if (w == 0)    *((float4*)(pd + rr * PW)) = e;
                    if (w == WW-1) *((float4*)(pd + rr * PW + PAD + WW)) = e;
                }
            }
            if (h == HH-1) {
                #pragma unroll
                for (int rr = 0; rr < PAD; ++rr) {
                    int r2 = (PH - 1 - rr) * PW;
                    pd[r2 + PAD + w] = r;
                    if (w == 0)    *((float4*)(pd + r2)) = e;
                    if (w == WW-1) *((float4*)(pd + r2 + PAD + WW)) = e;
                }
            }
        }
    }
}

extern "C" void kernel_launch(void* const* d_in, const int* in_sizes, int n_in,
                              void* d_out, int out_size, void* d_ws, size_t ws_size,
                              hipStream_t stream) {
    const float* feats = (const float*)d_in[0];
    const float* mask  = (const float*)d_in[1];
    float* out = (float*)d_out;

    const size_t affE  = (size_t)BB * 6 * NPIX * 4;     // 1.57 M floats
    const size_t pbufE = (size_t)BB * CHN * PPLANE;     // 1.55 M floats

    float* aff    = (float*)d_ws;
    float* pbuf0  = aff + affE;
    float* pbuf1  = pbuf0 + pbufE;
    float* pfeats = pbuf1 + pbufE;

    {
        int total = (BB * CC + BB * CHN) * PH * PWQ;
        pad_kernel<<<dim3((total + 255) / 256), dim3(256), 0, stream>>>(feats, mask, pfeats, pbuf0);
    }
    affinity_kernel<<<dim3(BB * NPIX / 64), dim3(256), 0, stream>>>(pfeats, aff);

    const float* src = pbuf0;
    for (int it = 1; it <= 10; ++it) {
        if (it < 10) {
            float* dst = (it & 1) ? pbuf1 : pbuf0;
            prop_kernel<<<dim3(256, NCG), dim3(256), 0, stream>>>(src, aff, dst, 0);
            src = dst;
        } else {
            prop_kernel<<<dim3(256, NCG), dim3(256), 0, stream>>>(src, aff, out, 1);
        }
    }
}

// Round 8
// 136.672 us; speedup vs baseline: 1.0405x; 1.0405x over previous
//
#include <hip/hip_runtime.h>
#include <hip/hip_cooperative_groups.h>

#define HH 128
#define WW 128
#define BB 4
#define CC 64
#define CHN 21
#define NPIX (HH*WW)     // 16384
#define NTAP 24
#define PAD 4
#define PW 136
#define PH 136
#define PPLANE (PW*PH)   // 18496
#define PWQ (PW/4)       // 34
#define AGR 4            // affinity channel groups per block
#define ACH (CC/AGR)     // 16 channels per thread
#define COOP_BLOCKS 1792 // 65536 px * 7 cg / 256

// Compile-time tap offsets in the padded plane (row stride PW).
constexpr int TAPOFF[NTAP] = {
    -PW-1, -PW, -PW+1, -1, 1, PW-1, PW, PW+1,
    -2*PW-2, -2*PW, -2*PW+2, -2, 2, 2*PW-2, 2*PW, 2*PW+2,
    -4*PW-4, -4*PW, -4*PW+4, -4, 4, 4*PW-4, 4*PW, 4*PW+4
};

__device__ __forceinline__ int clampi(int v, int lo, int hi) {
    return v < lo ? lo : (v > hi ? hi : v);
}

// ---- pad: edge-replicate feats AND mask into padded planes in one launch ---
__global__ __launch_bounds__(256) void pad_kernel(
    const float* __restrict__ feats, const float* __restrict__ mask,
    float* __restrict__ pfeats, float* __restrict__ pmask) {
    int t = blockIdx.x * blockDim.x + threadIdx.x;
    const int nfp = BB * CC;
    const int total = (nfp + BB * CHN) * PH * PWQ;
    if (t >= total) return;
    int q = t % PWQ;
    int rest = t / PWQ;
    int ph = rest % PH;
    int pl = rest / PH;
    const float* src;
    float* dst;
    if (pl < nfp) { src = feats + (size_t)pl * NPIX; dst = pfeats + (size_t)pl * PPLANE; }
    else { src = mask + (size_t)(pl - nfp) * NPIX; dst = pmask + (size_t)(pl - nfp) * PPLANE; }
    const float* sp = src + (size_t)clampi(ph - PAD, 0, HH - 1) * WW;
    float4 v;
    v.x = sp[clampi(q * 4 + 0 - PAD, 0, WW - 1)];
    v.y = sp[clampi(q * 4 + 1 - PAD, 0, WW - 1)];
    v.z = sp[clampi(q * 4 + 2 - PAD, 0, WW - 1)];
    v.w = sp[clampi(q * 4 + 3 - PAD, 0, WW - 1)];
    *((float4*)(dst + (size_t)ph * PW + q * 4)) = v;
}

// ---- fused affinity: block = 64 px x 4 channel-groups; LDS reduce ----------
// aff output layout: [b][6][NPIX][4] (tap-quad SoA, coalesced for prop).
__global__ __launch_bounds__(256) void affinity_kernel(
    const float* __restrict__ pfeats, float* __restrict__ aff) {
    __shared__ float red[AGR][64][NTAP + 1];   // stride 25: conflict-free

    int t = threadIdx.x;
    int g = t >> 6;                  // 0..3 channel group
    int px = t & 63;                 // 0..63 pixel in half-row
    int blk = blockIdx.x;            // 0..1023
    int w = (blk & 1) * 64 + px;
    int h = (blk >> 1) & 127;
    int b = blk >> 8;

    const float* base0 = pfeats + (size_t)(b * CC + g * ACH) * PPLANE
                       + (size_t)(h + PAD) * PW + (w + PAD);

    float acc[NTAP];
    #pragma unroll
    for (int k = 0; k < NTAP; ++k) acc[k] = 0.f;

    for (int c = 0; c < ACH; ++c) {
        const float* base = base0 + (size_t)c * PPLANE;
        float q = base[0];
        float sum = 3.f * q, ss = 3.f * q * q;   // center window x3 dilations
        float v[NTAP];
        #pragma unroll
        for (int k = 0; k < NTAP; ++k) {
            float x = base[TAPOFF[k]];
            v[k] = x;
            sum += x;
            ss = fmaf(x, x, ss);
        }
        float var = (ss - sum * sum * (1.f/27.f)) * (1.f/26.f);
        float inv = 1.f / (1e-8f + 0.1f * sqrtf(fmaxf(var, 0.f)));
        #pragma unroll
        for (int k = 0; k < NTAP; ++k)
            acc[k] = fmaf(fabsf(v[k] - q), inv, acc[k]);   // positive sum; negate later
    }

    #pragma unroll
    for (int k = 0; k < NTAP; ++k) red[g][px][k] = acc[k];
    __syncthreads();

    if (t < 64) {
        float s[NTAP];
        #pragma unroll
        for (int k = 0; k < NTAP; ++k)
            s[k] = (red[0][t][k] + red[1][t][k]) + (red[2][t][k] + red[3][t][k]);
        float mn = s[0];
        #pragma unroll
        for (int k = 1; k < NTAP; ++k) mn = fminf(mn, s[k]);
        float e[NTAP];
        float tot = 0.f;
        #pragma unroll
        for (int k = 0; k < NTAP; ++k) {
            e[k] = __expf((mn - s[k]) * (1.f/CC));
            tot += e[k];
        }
        float ivt = 1.f / tot;
        int pix = h * WW + (blk & 1) * 64 + t;
        #pragma unroll
        for (int j = 0; j < 6; ++j) {
            float4 o = make_float4(e[4*j]*ivt, e[4*j+1]*ivt, e[4*j+2]*ivt, e[4*j+3]*ivt);
            *((float4*)(aff + (((size_t)b * 6 + j) * NPIX + pix) * 4)) = o;
        }
    }
}

// ---- shared per-pixel propagation body -------------------------------------
__device__ __forceinline__ void prop_px(
    const float* __restrict__ src, float* __restrict__ dst, int final_iter,
    const float* A, int b, int ch, int h, int w, int pix) {
    const float* base = src + (size_t)(b * CHN + ch) * PPLANE
                      + (size_t)(h + PAD) * PW + (w + PAD);
    float r = 0.f;
    #pragma unroll
    for (int k = 0; k < NTAP; ++k) r = fmaf(A[k], base[TAPOFF[k]], r);

    if (final_iter) {
        dst[(size_t)(b * CHN + ch) * NPIX + pix] = r;
    } else {
        float* pd = dst + (size_t)(b * CHN + ch) * PPLANE;
        int pr = (h + PAD) * PW;
        pd[pr + PAD + w] = r;
        float4 e = make_float4(r, r, r, r);
        if (w == 0)      *((float4*)(pd + pr)) = e;
        if (w == WW-1)   *((float4*)(pd + pr + PAD + WW)) = e;
        if (h == 0) {
            #pragma unroll
            for (int rr = 0; rr < PAD; ++rr) {
                pd[rr * PW + PAD + w] = r;
                if (w == 0)    *((float4*)(pd + rr * PW)) = e;
                if (w == WW-1) *((float4*)(pd + rr * PW + PAD + WW)) = e;
            }
        }
        if (h == HH-1) {
            #pragma unroll
            for (int rr = 0; rr < PAD; ++rr) {
                int r2 = (PH - 1 - rr) * PW;
                pd[r2 + PAD + w] = r;
                if (w == 0)    *((float4*)(pd + r2)) = e;
                if (w == WW-1) *((float4*)(pd + r2 + PAD + WW)) = e;
            }
        }
    }
}

// ---- cooperative: all 10 iterations in one kernel --------------------------
// thread = (pixel, channel-group of 3); aff loaded once into registers.
__global__ __launch_bounds__(256, 7) void prop_coop_kernel(
    const float* __restrict__ aff, float* __restrict__ pb0,
    float* __restrict__ pb1, float* __restrict__ out) {
    int tid = blockIdx.x * 256 + threadIdx.x;   // 0..458751
    int cg = tid >> 16;                          // 0..6
    int gpx = tid & 65535;
    int w = gpx & 127;
    int h = (gpx >> 7) & 127;
    int b = gpx >> 14;
    int pix = gpx & (NPIX - 1);

    float A[NTAP];
    #pragma unroll
    for (int j = 0; j < 6; ++j) {
        float4 v = *((const float4*)(aff + (((size_t)b * 6 + j) * NPIX + pix) * 4));
        A[4*j] = v.x; A[4*j+1] = v.y; A[4*j+2] = v.z; A[4*j+3] = v.w;
    }

    cooperative_groups::grid_group grid = cooperative_groups::this_grid();

    const float* src = pb0;
    for (int it = 1; it <= 10; ++it) {
        int fin = (it == 10);
        float* dst = fin ? out : ((it & 1) ? pb1 : pb0);
        #pragma unroll
        for (int cc = 0; cc < 3; ++cc)
            prop_px(src, dst, fin, A, b, cg * 3 + cc, h, w, pix);
        if (!fin) {
            __threadfence();
            grid.sync();
            src = dst;
        }
    }
}

// ---- fallback: one iteration per launch ------------------------------------
__global__ __launch_bounds__(256) void prop_kernel(
    const float* __restrict__ psrc_all, const float* __restrict__ aff,
    float* __restrict__ dst, int final_iter) {
    int idx = blockIdx.x * 256 + threadIdx.x;
    int cg = blockIdx.y;                        // 0..6
    int w = idx & 127;
    int h = (idx >> 7) & 127;
    int b = idx >> 14;
    int pix = idx & (NPIX - 1);

    float A[NTAP];
    #pragma unroll
    for (int j = 0; j < 6; ++j) {
        float4 v = *((const float4*)(aff + (((size_t)b * 6 + j) * NPIX + pix) * 4));
        A[4*j] = v.x; A[4*j+1] = v.y; A[4*j+2] = v.z; A[4*j+3] = v.w;
    }
    #pragma unroll
    for (int cc = 0; cc < 3; ++cc)
        prop_px(psrc_all, dst, final_iter, A, b, cg * 3 + cc, h, w, pix);
}

extern "C" void kernel_launch(void* const* d_in, const int* in_sizes, int n_in,
                              void* d_out, int out_size, void* d_ws, size_t ws_size,
                              hipStream_t stream) {
    const float* feats = (const float*)d_in[0];
    const float* mask  = (const float*)d_in[1];
    float* out = (float*)d_out;

    const size_t affE  = (size_t)BB * 6 * NPIX * 4;     // 1.57 M floats
    const size_t pbufE = (size_t)BB * CHN * PPLANE;     // 1.55 M floats

    float* aff    = (float*)d_ws;
    float* pbuf0  = aff + affE;
    float* pbuf1  = pbuf0 + pbufE;
    float* pfeats = pbuf1 + pbufE;

    {
        int total = (BB * CC + BB * CHN) * PH * PWQ;
        pad_kernel<<<dim3((total + 255) / 256), dim3(256), 0, stream>>>(feats, mask, pfeats, pbuf0);
    }
    affinity_kernel<<<dim3(BB * NPIX / 64), dim3(256), 0, stream>>>(pfeats, aff);

    // Cooperative path requires all 1792 blocks co-resident (7 per CU).
    int dev = 0, coop = 0, occBlocks = 0;
    hipGetDevice(&dev);
    hipDeviceGetAttribute(&coop, hipDeviceAttributeCooperativeLaunch, dev);
    hipOccupancyMaxActiveBlocksPerMultiprocessor(&occBlocks, prop_coop_kernel, 256, 0);

    if (coop && occBlocks >= 7) {
        void* args[] = { (void*)&aff, (void*)&pbuf0, (void*)&pbuf1, (void*)&out };
        hipLaunchCooperativeKernel((const void*)prop_coop_kernel,
                                   dim3(COOP_BLOCKS), dim3(256), args, 0, stream);
    } else {
        const float* src = pbuf0;
        for (int it = 1; it <= 10; ++it) {
            if (it < 10) {
                float* dst = (it & 1) ? pbuf1 : pbuf0;
                prop_kernel<<<dim3(256, 7), dim3(256), 0, stream>>>(src, aff, dst, 0);
                src = dst;
            } else {
                prop_kernel<<<dim3(256, 7), dim3(256), 0, stream>>>(src, aff, out, 1);
            }
        }
    }
}

// Round 9
// 131.499 us; speedup vs baseline: 1.0815x; 1.0393x over previous
//
#include <hip/hip_runtime.h>

#define HH 128
#define WW 128
#define BB 4
#define CC 64
#define CHN 21
#define NPIX (HH*WW)     // 16384
#define NTAP 24
#define PAD 4
#define PW 136
#define PH 136
#define PPLANE (PW*PH)   // 18496
#define PWQ (PW/4)       // 34
#define AGR 4            // affinity channel groups per block
#define ACH (CC/AGR)     // 16 channels per thread

typedef _Float16 h8 __attribute__((ext_vector_type(8)));

// Compile-time tap offsets in the padded plane (row stride PW).
constexpr int TAPOFF[NTAP] = {
    -PW-1, -PW, -PW+1, -1, 1, PW-1, PW, PW+1,
    -2*PW-2, -2*PW, -2*PW+2, -2, 2, 2*PW-2, 2*PW, 2*PW+2,
    -4*PW-4, -4*PW, -4*PW+4, -4, 4, 4*PW-4, 4*PW, 4*PW+4
};

__device__ __forceinline__ int clampi(int v, int lo, int hi) {
    return v < lo ? lo : (v > hi ? hi : v);
}

// ---- pad: edge-replicate feats AND mask into padded f32 planes -------------
__global__ __launch_bounds__(256) void pad_kernel(
    const float* __restrict__ feats, const float* __restrict__ mask,
    float* __restrict__ pfeats, float* __restrict__ pmask) {
    int t = blockIdx.x * blockDim.x + threadIdx.x;
    const int nfp = BB * CC;
    const int total = (nfp + BB * CHN) * PH * PWQ;
    if (t >= total) return;
    int q = t % PWQ;
    int rest = t / PWQ;
    int ph = rest % PH;
    int pl = rest / PH;
    const float* src;
    float* dst;
    if (pl < nfp) { src = feats + (size_t)pl * NPIX; dst = pfeats + (size_t)pl * PPLANE; }
    else { src = mask + (size_t)(pl - nfp) * NPIX; dst = pmask + (size_t)(pl - nfp) * PPLANE; }
    const float* sp = src + (size_t)clampi(ph - PAD, 0, HH - 1) * WW;
    float4 v;
    v.x = sp[clampi(q * 4 + 0 - PAD, 0, WW - 1)];
    v.y = sp[clampi(q * 4 + 1 - PAD, 0, WW - 1)];
    v.z = sp[clampi(q * 4 + 2 - PAD, 0, WW - 1)];
    v.w = sp[clampi(q * 4 + 3 - PAD, 0, WW - 1)];
    *((float4*)(dst + (size_t)ph * PW + q * 4)) = v;
}

// ---- fused affinity: block = 64 px x 4 channel-groups; LDS reduce ----------
// aff output: h8 quads, layout [b][3][NPIX] (each quad = 8 taps, fp16).
__global__ __launch_bounds__(256) void affinity_kernel(
    const float* __restrict__ pfeats, h8* __restrict__ aff) {
    __shared__ float red[AGR][64][NTAP + 1];   // stride 25: conflict-free

    int t = threadIdx.x;
    int g = t >> 6;                  // 0..3 channel group
    int px = t & 63;                 // 0..63 pixel in half-row
    int blk = blockIdx.x;            // 0..1023
    int w = (blk & 1) * 64 + px;
    int h = (blk >> 1) & 127;
    int b = blk >> 8;

    const float* base0 = pfeats + (size_t)(b * CC + g * ACH) * PPLANE
                       + (size_t)(h + PAD) * PW + (w + PAD);

    float acc[NTAP];
    #pragma unroll
    for (int k = 0; k < NTAP; ++k) acc[k] = 0.f;

    for (int c = 0; c < ACH; ++c) {
        const float* base = base0 + (size_t)c * PPLANE;
        float q = base[0];
        float sum = 3.f * q, ss = 3.f * q * q;   // center window x3 dilations
        float v[NTAP];
        #pragma unroll
        for (int k = 0; k < NTAP; ++k) {
            float x = base[TAPOFF[k]];
            v[k] = x;
            sum += x;
            ss = fmaf(x, x, ss);
        }
        float var = (ss - sum * sum * (1.f/27.f)) * (1.f/26.f);
        float inv = 1.f / (1e-8f + 0.1f * sqrtf(fmaxf(var, 0.f)));
        #pragma unroll
        for (int k = 0; k < NTAP; ++k)
            acc[k] = fmaf(fabsf(v[k] - q), inv, acc[k]);   // positive sum; negate later
    }

    #pragma unroll
    for (int k = 0; k < NTAP; ++k) red[g][px][k] = acc[k];
    __syncthreads();

    if (t < 64) {
        float s[NTAP];
        #pragma unroll
        for (int k = 0; k < NTAP; ++k)
            s[k] = (red[0][t][k] + red[1][t][k]) + (red[2][t][k] + red[3][t][k]);
        float mn = s[0];
        #pragma unroll
        for (int k = 1; k < NTAP; ++k) mn = fminf(mn, s[k]);
        float e[NTAP];
        float tot = 0.f;
        #pragma unroll
        for (int k = 0; k < NTAP; ++k) {
            e[k] = __expf((mn - s[k]) * (1.f/CC));
            tot += e[k];
        }
        float ivt = 1.f / tot;
        int pix = h * WW + (blk & 1) * 64 + t;
        #pragma unroll
        for (int j = 0; j < 3; ++j) {
            h8 q;
            #pragma unroll
            for (int i = 0; i < 8; ++i) q[i] = (_Float16)(e[8*j + i] * ivt);
            aff[((size_t)b * 3 + j) * NPIX + pix] = q;
        }
    }
}

// ---- shared per-pixel propagation body -------------------------------------
__device__ __forceinline__ void prop_px(
    const float* __restrict__ src, float* __restrict__ dst, int final_iter,
    const float* A, int b, int ch, int h, int w, int pix) {
    const float* base = src + (size_t)(b * CHN + ch) * PPLANE
                      + (size_t)(h + PAD) * PW + (w + PAD);
    float r = 0.f;
    #pragma unroll
    for (int k = 0; k < NTAP; ++k) r = fmaf(A[k], base[TAPOFF[k]], r);

    if (final_iter) {
        dst[(size_t)(b * CHN + ch) * NPIX + pix] = r;
    } else {
        float* pd = dst + (size_t)(b * CHN + ch) * PPLANE;
        int pr = (h + PAD) * PW;
        pd[pr + PAD + w] = r;
        float4 e = make_float4(r, r, r, r);
        if (w == 0)      *((float4*)(pd + pr)) = e;
        if (w == WW-1)   *((float4*)(pd + pr + PAD + WW)) = e;
        if (h == 0) {
            #pragma unroll
            for (int rr = 0; rr < PAD; ++rr) {
                pd[rr * PW + PAD + w] = r;
                if (w == 0)    *((float4*)(pd + rr * PW)) = e;
                if (w == WW-1) *((float4*)(pd + rr * PW + PAD + WW)) = e;
            }
        }
        if (h == HH-1) {
            #pragma unroll
            for (int rr = 0; rr < PAD; ++rr) {
                int r2 = (PH - 1 - rr) * PW;
                pd[r2 + PAD + w] = r;
                if (w == 0)    *((float4*)(pd + r2)) = e;
                if (w == WW-1) *((float4*)(pd + r2 + PAD + WW)) = e;
            }
        }
    }
}

// ---- prop: 1 px x 3 ch per thread; fp16 h8 aff (coalesced) -----------------
__global__ __launch_bounds__(256, 7) void prop_kernel(
    const float* __restrict__ psrc_all, const h8* __restrict__ aff,
    float* __restrict__ dst, int final_iter) {
    int idx = blockIdx.x * 256 + threadIdx.x;   // global px 0..65535
    int cg = blockIdx.y;                        // 0..6
    int w = idx & 127;
    int h = (idx >> 7) & 127;
    int b = idx >> 14;
    int pix = idx & (NPIX - 1);

    float A[NTAP];
    #pragma unroll
    for (int j = 0; j < 3; ++j) {
        h8 q = aff[((size_t)b * 3 + j) * NPIX + pix];
        #pragma unroll
        for (int i = 0; i < 8; ++i) A[8*j + i] = (float)q[i];
    }

    #pragma unroll
    for (int cc = 0; cc < 3; ++cc)
        prop_px(psrc_all, dst, final_iter, A, b, cg * 3 + cc, h, w, pix);
}

extern "C" void kernel_launch(void* const* d_in, const int* in_sizes, int n_in,
                              void* d_out, int out_size, void* d_ws, size_t ws_size,
                              hipStream_t stream) {
    const float* feats = (const float*)d_in[0];
    const float* mask  = (const float*)d_in[1];
    float* out = (float*)d_out;

    const size_t pfeatsE = (size_t)BB * CC * PPLANE;            // f32 elems
    const size_t affQ    = (size_t)BB * 3 * NPIX;               // h8 elems (16B each)
    const size_t pbufE   = (size_t)BB * CHN * PPLANE;           // f32 elems

    float* pfeats = (float*)d_ws;
    h8*    aff    = (h8*)(pfeats + pfeatsE);
    float* pbuf0  = (float*)((char*)aff + affQ * sizeof(h8));
    float* pbuf1  = pbuf0 + pbufE;

    {
        int total = (BB * CC + BB * CHN) * PH * PWQ;
        pad_kernel<<<dim3((total + 255) / 256), dim3(256), 0, stream>>>(feats, mask, pfeats, pbuf0);
    }
    affinity_kernel<<<dim3(BB * NPIX / 64), dim3(256), 0, stream>>>(pfeats, aff);

    const float* src = pbuf0;
    for (int it = 1; it <= 10; ++it) {
        if (it < 10) {
            float* dst = (it & 1) ? pbuf1 : pbuf0;
            prop_kernel<<<dim3(256, 7), dim3(256), 0, stream>>>(src, aff, dst, 0);
            src = dst;
        } else {
            prop_kernel<<<dim3(256, 7), dim3(256), 0, stream>>>(src, aff, out, 1);
        }
    }
}